// Round 7
// baseline (443.229 us; speedup 1.0000x reference)
//
#include <hip/hip_runtime.h>
#include <hip/hip_fp8.h>

#define EMB 1024
#define HID 4096
#define NB 2
#define TT 4096
#define MROWS (NB*TT)   // 8192
#define N1 (2*HID)      // 8192
#define CHUNK 128       // = GEMM1 row tile
#define NCH 32          // chunks per batch (TT/CHUNK)

typedef short short8 __attribute__((ext_vector_type(8)));
typedef float v4f   __attribute__((ext_vector_type(4)));

__device__ __forceinline__ unsigned short f2bf(float f) {
  unsigned int u = __float_as_uint(f);
  u += 0x7FFFu + ((u >> 16) & 1u);
  return (unsigned short)(u >> 16);
}
__device__ __forceinline__ float bf2f(unsigned short s) {
  return __uint_as_float(((unsigned int)s) << 16);
}
__device__ __forceinline__ unsigned char f2e4m3(float f) {
  __hip_fp8_e4m3 q(f);
  return *(unsigned char*)&q;
}
__device__ __forceinline__ float e4m32f(unsigned char c) {
  __hip_fp8_e4m3 q = *(__hip_fp8_e4m3*)&c;
  return (float)q;
}
__device__ __forceinline__ void g2l16(const void* g, void* l) {
  __builtin_amdgcn_global_load_lds(
      (const __attribute__((address_space(1))) void*)g,
      (__attribute__((address_space(3))) void*)l, 16, 0, 0);
}

__device__ __forceinline__ float block_reduce_sum(float v, float* sbuf) {
  #pragma unroll
  for (int off = 32; off; off >>= 1) v += __shfl_down(v, off, 64);
  int lane = threadIdx.x & 63, w = threadIdx.x >> 6;
  if (lane == 0) sbuf[w] = v;
  __syncthreads();
  return sbuf[0] + sbuf[1] + sbuf[2] + sbuf[3];
}

// ---------- merged weight convert: W1|W2 -> w12_bf, W3 -> w3_bf ----------
__global__ __launch_bounds__(256) void conv_all(const float* __restrict__ W1,
                                                const float* __restrict__ W2,
                                                const float* __restrict__ W3,
                                                unsigned short* __restrict__ o12,
                                                unsigned short* __restrict__ o3) {
  size_t i = ((size_t)blockIdx.x*256 + threadIdx.x)*4;
  const float* s; unsigned short* d;
  if (i < (size_t)HID*EMB)        { s = W1 + i;                      d = o12 + i; }
  else if (i < 2ull*HID*EMB)      { s = W2 + (i - (size_t)HID*EMB);  d = o12 + i; }
  else                            { s = W3 + (i - 2ull*HID*EMB);     d = o3 + (i - 2ull*HID*EMB); }
  float4 v = *(const float4*)s;
  ushort4 u; u.x=f2bf(v.x); u.y=f2bf(v.y); u.z=f2bf(v.z); u.w=f2bf(v.w);
  *(ushort4*)d = u;
}

// ---------- rmsnorm (fp32 in, bf16 out), row = EMB ----------
__global__ __launch_bounds__(256) void rmsnorm_x(const float* __restrict__ x,
                                                 unsigned short* __restrict__ r) {
  __shared__ float sbuf[4];
  int row = blockIdx.x;
  float4 v = *(const float4*)(x + (size_t)row*EMB + threadIdx.x*4);
  float ss = v.x*v.x + v.y*v.y + v.z*v.z + v.w*v.w;
  float tot = block_reduce_sum(ss, sbuf);
  float sc = rsqrtf(tot * (1.0f/EMB) + 1e-6f);
  ushort4 o; o.x=f2bf(v.x*sc); o.y=f2bf(v.y*sc); o.z=f2bf(v.z*sc); o.w=f2bf(v.w*sc);
  *(ushort4*)(r + (size_t)row*EMB + threadIdx.x*4) = o;
}

// ---------- zero the ssq accumulator ----------
__global__ __launch_bounds__(256) void zero_ssq(float* __restrict__ ssq) {
  ssq[blockIdx.x*256 + threadIdx.x] = 0.f;
}

// ---------- ssq -> rsqrt scale, in place ----------
__global__ __launch_bounds__(256) void sc_from_ssq(float* __restrict__ ssq) {
  int row = blockIdx.x*256 + threadIdx.x;
  ssq[row] = rsqrtf(ssq[row]*(1.0f/HID) + 1e-6f);
}

// ---------- GEMM1: C8 = (fp8 e4m3) exp(A*Bt^T); col-chunk sums -> part ----------
// 128x128 tile, BK=64, 256 thr (4 waves, 2x2 of 64x64), XOR-swizzled LDS (32 KB).
__global__ __launch_bounds__(256, 2)
void gemm_exp(const unsigned short* __restrict__ A,
              const unsigned short* __restrict__ Bt,
              unsigned char* __restrict__ C8,
              float* __restrict__ part,
              int K, int N) {
  __shared__ short lA[128*64];
  __shared__ short lB[128*64];
  const int tid  = threadIdx.x;
  const int lane = tid & 63;
  const int wm   = (tid >> 6) >> 1, wn = (tid >> 6) & 1;
  const int rowBase = blockIdx.y * 128;
  const int colBase = blockIdx.x * 128;

  v4f acc[4][4];
  #pragma unroll
  for (int i=0;i<4;++i)
    #pragma unroll
    for (int j=0;j<4;++j) acc[i][j] = (v4f){0.f,0.f,0.f,0.f};

  for (int k0 = 0; k0 < K; k0 += 64) {
    #pragma unroll
    for (int j = 0; j < 4; ++j) {
      int s = j*256 + tid;
      int m = s >> 3;
      int c = (s & 7) ^ (m & 7);
      g2l16(A + (size_t)(rowBase + m)*K + k0 + c*8, &lA[s*8]);
    }
    #pragma unroll
    for (int j = 0; j < 4; ++j) {
      int s = j*256 + tid;
      int m = s >> 3;
      int c = (s & 7) ^ (m & 7);
      g2l16(Bt + (size_t)(colBase + m)*K + k0 + c*8, &lB[s*8]);
    }
    __syncthreads();
    #pragma unroll
    for (int s2 = 0; s2 < 2; ++s2) {
      const int quad = lane >> 4;
      const int cc = s2*4 + quad;
      short8 aF[4], bF[4];
      #pragma unroll
      for (int mt = 0; mt < 4; ++mt) {
        int ml = wm*64 + mt*16 + (lane & 15);
        aF[mt] = *(const short8*)&lA[(ml*8 + (cc ^ (ml & 7)))*8];
      }
      #pragma unroll
      for (int nt = 0; nt < 4; ++nt) {
        int nl = wn*64 + nt*16 + (lane & 15);
        bF[nt] = *(const short8*)&lB[(nl*8 + (cc ^ (nl & 7)))*8];
      }
      #pragma unroll
      for (int mt = 0; mt < 4; ++mt)
        #pragma unroll
        for (int nt = 0; nt < 4; ++nt)
          acc[mt][nt] = __builtin_amdgcn_mfma_f32_16x16x32_bf16(aF[mt], bF[nt], acc[mt][nt], 0, 0, 0);
    }
    __syncthreads();
  }

  const int quad = lane >> 4, c15 = lane & 15;
  float csum[4] = {0.f, 0.f, 0.f, 0.f};
  #pragma unroll
  for (int mt = 0; mt < 4; ++mt) {
    #pragma unroll
    for (int nt = 0; nt < 4; ++nt) {
      int col = colBase + wn*64 + nt*16 + c15;
      #pragma unroll
      for (int r = 0; r < 4; ++r) {
        int row = rowBase + wm*64 + mt*16 + quad*4 + r;
        size_t idx = (size_t)row*N + col;
        float e = __expf(acc[mt][nt][r]);
        C8[idx] = f2e4m3(e);
        csum[nt] += e;
      }
    }
  }
  // epilogue column sums; cs reuses lA (dead after final barrier above)
  float* cs = (float*)lA;   // [2][128]
  #pragma unroll
  for (int nt = 0; nt < 4; ++nt) {
    float s = csum[nt];
    s += __shfl_xor(s, 16, 64);
    s += __shfl_xor(s, 32, 64);
    if (lane < 16) cs[wm*128 + wn*64 + nt*16 + lane] = s;
  }
  __syncthreads();
  if (tid < 128)
    part[(size_t)(colBase + tid)*64 + blockIdx.y] = cs[tid] + cs[128 + tid];
}

// ---------- GEMM2: out[row][col] = Sc[row]*(A*Bt^T) + X ----------
__global__ __launch_bounds__(256, 2)
void gemm_out(const unsigned short* __restrict__ A,
              const unsigned short* __restrict__ Bt,
              float* __restrict__ Cf,
              const float* __restrict__ X,
              const float* __restrict__ Sc,
              int K, int N) {
  __shared__ short lA[128*64];
  __shared__ short lB[128*64];
  const int tid  = threadIdx.x;
  const int lane = tid & 63;
  const int wm   = (tid >> 6) >> 1, wn = (tid >> 6) & 1;
  const int rowBase = blockIdx.y * 128;
  const int colBase = blockIdx.x * 128;

  v4f acc[4][4];
  #pragma unroll
  for (int i=0;i<4;++i)
    #pragma unroll
    for (int j=0;j<4;++j) acc[i][j] = (v4f){0.f,0.f,0.f,0.f};

  for (int k0 = 0; k0 < K; k0 += 64) {
    #pragma unroll
    for (int j = 0; j < 4; ++j) {
      int s = j*256 + tid;
      int m = s >> 3;
      int c = (s & 7) ^ (m & 7);
      g2l16(A + (size_t)(rowBase + m)*K + k0 + c*8, &lA[s*8]);
    }
    #pragma unroll
    for (int j = 0; j < 4; ++j) {
      int s = j*256 + tid;
      int m = s >> 3;
      int c = (s & 7) ^ (m & 7);
      g2l16(Bt + (size_t)(colBase + m)*K + k0 + c*8, &lB[s*8]);
    }
    __syncthreads();
    #pragma unroll
    for (int s2 = 0; s2 < 2; ++s2) {
      const int quad = lane >> 4;
      const int cc = s2*4 + quad;
      short8 aF[4], bF[4];
      #pragma unroll
      for (int mt = 0; mt < 4; ++mt) {
        int ml = wm*64 + mt*16 + (lane & 15);
        aF[mt] = *(const short8*)&lA[(ml*8 + (cc ^ (ml & 7)))*8];
      }
      #pragma unroll
      for (int nt = 0; nt < 4; ++nt) {
        int nl = wn*64 + nt*16 + (lane & 15);
        bF[nt] = *(const short8*)&lB[(nl*8 + (cc ^ (nl & 7)))*8];
      }
      #pragma unroll
      for (int mt = 0; mt < 4; ++mt)
        #pragma unroll
        for (int nt = 0; nt < 4; ++nt)
          acc[mt][nt] = __builtin_amdgcn_mfma_f32_16x16x32_bf16(aF[mt], bF[nt], acc[mt][nt], 0, 0, 0);
    }
    __syncthreads();
  }

  const int quad = lane >> 4, c15 = lane & 15;
  #pragma unroll
  for (int mt = 0; mt < 4; ++mt) {
    #pragma unroll
    for (int nt = 0; nt < 4; ++nt) {
      int col = colBase + wn*64 + nt*16 + c15;
      #pragma unroll
      for (int r = 0; r < 4; ++r) {
        int row = rowBase + wm*64 + mt*16 + quad*4 + r;
        size_t idx = (size_t)row*N + col;
        Cf[idx] = Sc[row]*acc[mt][nt][r] + X[idx];
      }
    }
  }
}

// ---------- exclusive prefix over 32 chunks per (col, batch) ----------
__global__ __launch_bounds__(256) void scan_prefix(float* __restrict__ part) {
  int idx = blockIdx.x*256 + threadIdx.x;   // 0..16383
  int col = idx >> 1, bb = idx & 1;
  float* p = part + (size_t)col*64 + bb*NCH;
  float run = 0.f;
  #pragma unroll
  for (int c = 0; c < NCH; ++c) { float v = p[c]; p[c] = run; run += v; }
}

// ---------- emit y = Sa*Sb/t^2 (bf16) from fp8 exp values; fused row-ssq ----------
__global__ __launch_bounds__(256) void scan_emit(const unsigned char* __restrict__ ab,
                                                 const float* __restrict__ part,
                                                 unsigned short* __restrict__ y,
                                                 float* __restrict__ ssq) {
  int h = blockIdx.x*256 + threadIdx.x;     // 0..4095
  int cy = blockIdx.y, bb = blockIdx.z;
  int lane = threadIdx.x & 63;
  float sa = part[(size_t)h*64 + bb*NCH + cy];
  float sb = part[(size_t)(HID + h)*64 + bb*NCH + cy];
  const unsigned char* pa = ab + ((size_t)(bb*TT + cy*CHUNK))*N1 + h;
  const unsigned char* pb = pa + HID;
  unsigned short* py = y + ((size_t)(bb*TT + cy*CHUNK))*HID + h;
  int t0 = cy*CHUNK;
  for (int i = 0; i < CHUNK; ++i) {
    sa += e4m32f(pa[(size_t)i*N1]);
    sb += e4m32f(pb[(size_t)i*N1]);
    float inv = 1.0f / (float)(t0 + i + 1);
    float yv = sa*sb*inv*inv;
    py[(size_t)i*HID] = f2bf(yv);
    // fused sum-of-squares: wave reduce, one atomic per wave per row
    float s = yv*yv;
    #pragma unroll
    for (int off = 32; off; off >>= 1) s += __shfl_down(s, off, 64);
    if (lane == 0) unsafeAtomicAdd(&ssq[bb*TT + t0 + i], s);
  }
}

extern "C" void kernel_launch(void* const* d_in, const int* in_sizes, int n_in,
                              void* d_out, int out_size, void* d_ws, size_t ws_size,
                              hipStream_t stream) {
  const float* x  = (const float*)d_in[0];
  const float* W1 = (const float*)d_in[1];
  const float* W2 = (const float*)d_in[2];
  const float* W3 = (const float*)d_in[3];
  float* out = (float*)d_out;
  char* ws = (char*)d_ws;

  unsigned short* r_bf   = (unsigned short*)(ws);                 // 16 MB
  unsigned short* w12_bf = (unsigned short*)(ws + 16777216ull);   // 16 MB
  unsigned short* w3_bf  = (unsigned short*)(ws + 33554432ull);   // 8 MB
  unsigned char*  ab8    = (unsigned char*) (ws + 41943040ull);   // 64 MB fp8
  unsigned short* y_bf   = (unsigned short*)(ws + 109051904ull);  // 64 MB
  float*          ssq    = (float*)(ws + 176160768ull);           // 32 KB (ssq -> sc in place)
  // part (per-chunk column sums) lives in d_out; dead before gemm_out
  float*          part   = (float*)d_out;                         // 2 MB

  zero_ssq<<<32, 256, 0, stream>>>(ssq);
  conv_all<<<12288, 256, 0, stream>>>(W1, W2, W3, w12_bf, w3_bf);
  rmsnorm_x<<<MROWS, 256, 0, stream>>>(x, r_bf);
  gemm_exp<<<dim3(64,64), 256, 0, stream>>>(r_bf, w12_bf, ab8, part, EMB, N1);
  scan_prefix<<<64, 256, 0, stream>>>(part);
  scan_emit<<<dim3(16,NCH,2), 256, 0, stream>>>(ab8, part, y_bf, ssq);
  sc_from_ssq<<<32, 256, 0, stream>>>(ssq);
  gemm_out<<<dim3(8,64), 256, 0, stream>>>(y_bf, w3_bf, out, x, ssq, HID, EMB);
}

// Round 8
// 407.141 us; speedup vs baseline: 1.0886x; 1.0886x over previous
//
#include <hip/hip_runtime.h>
#include <hip/hip_fp8.h>

#define EMB 1024
#define HID 4096
#define NB 2
#define TT 4096
#define MROWS (NB*TT)   // 8192
#define N1 (2*HID)      // 8192
#define CHUNK 128       // = GEMM1 row tile
#define NCH 32          // chunks per batch (TT/CHUNK)

typedef short short8 __attribute__((ext_vector_type(8)));
typedef float v4f   __attribute__((ext_vector_type(4)));

__device__ __forceinline__ unsigned short f2bf(float f) {
  unsigned int u = __float_as_uint(f);
  u += 0x7FFFu + ((u >> 16) & 1u);
  return (unsigned short)(u >> 16);
}
__device__ __forceinline__ float bf2f(unsigned short s) {
  return __uint_as_float(((unsigned int)s) << 16);
}
__device__ __forceinline__ float h2f(unsigned short u) {
  return (float)(*(const _Float16*)&u);
}
__device__ __forceinline__ unsigned char f2e4m3(float f) {
  __hip_fp8_e4m3 q(f);
  return *(unsigned char*)&q;
}
__device__ __forceinline__ float e4m32f(unsigned char c) {
  __hip_fp8_e4m3 q = *(__hip_fp8_e4m3*)&c;
  return (float)q;
}
__device__ __forceinline__ void g2l16(const void* g, void* l) {
  __builtin_amdgcn_global_load_lds(
      (const __attribute__((address_space(1))) void*)g,
      (__attribute__((address_space(3))) void*)l, 16, 0, 0);
}

__device__ __forceinline__ float block_reduce_sum(float v, float* sbuf) {
  #pragma unroll
  for (int off = 32; off; off >>= 1) v += __shfl_down(v, off, 64);
  int lane = threadIdx.x & 63, w = threadIdx.x >> 6;
  if (lane == 0) sbuf[w] = v;
  __syncthreads();
  return sbuf[0] + sbuf[1] + sbuf[2] + sbuf[3];
}

// ---------- merged weight convert: W1|W2 -> w12_bf, W3 -> w3_bf ----------
__global__ __launch_bounds__(256) void conv_all(const float* __restrict__ W1,
                                                const float* __restrict__ W2,
                                                const float* __restrict__ W3,
                                                unsigned short* __restrict__ o12,
                                                unsigned short* __restrict__ o3) {
  size_t i = ((size_t)blockIdx.x*256 + threadIdx.x)*4;
  const float* s; unsigned short* d;
  if (i < (size_t)HID*EMB)        { s = W1 + i;                      d = o12 + i; }
  else if (i < 2ull*HID*EMB)      { s = W2 + (i - (size_t)HID*EMB);  d = o12 + i; }
  else                            { s = W3 + (i - 2ull*HID*EMB);     d = o3 + (i - 2ull*HID*EMB); }
  float4 v = *(const float4*)s;
  ushort4 u; u.x=f2bf(v.x); u.y=f2bf(v.y); u.z=f2bf(v.z); u.w=f2bf(v.w);
  *(ushort4*)d = u;
}

// ---------- rmsnorm (fp32 in, bf16 out), row = EMB ----------
__global__ __launch_bounds__(256) void rmsnorm_x(const float* __restrict__ x,
                                                 unsigned short* __restrict__ r) {
  __shared__ float sbuf[4];
  int row = blockIdx.x;
  float4 v = *(const float4*)(x + (size_t)row*EMB + threadIdx.x*4);
  float ss = v.x*v.x + v.y*v.y + v.z*v.z + v.w*v.w;
  float tot = block_reduce_sum(ss, sbuf);
  float sc = rsqrtf(tot * (1.0f/EMB) + 1e-6f);
  ushort4 o; o.x=f2bf(v.x*sc); o.y=f2bf(v.y*sc); o.z=f2bf(v.z*sc); o.w=f2bf(v.w*sc);
  *(ushort4*)(r + (size_t)row*EMB + threadIdx.x*4) = o;
}

// ---------- row sum-of-squares -> rsqrt scale (bf16 in), row = HID ----------
__global__ __launch_bounds__(256) void rowssq(const unsigned short* __restrict__ y,
                                              float* __restrict__ sc) {
  __shared__ float sbuf[4];
  int row = blockIdx.x;
  const unsigned short* p = y + (size_t)row*HID + threadIdx.x*16;
  short8 v0 = *(const short8*)p;
  short8 v1 = *(const short8*)(p+8);
  float ss = 0.f;
  #pragma unroll
  for (int j=0;j<8;++j){ float a=bf2f((unsigned short)v0[j]), b=bf2f((unsigned short)v1[j]); ss += a*a + b*b; }
  float tot = block_reduce_sum(ss, sbuf);
  if (threadIdx.x == 0) sc[row] = rsqrtf(tot*(1.0f/HID) + 1e-6f);
}

// ---------- GEMM1: C8 = (fp8 e4m3) exp(A*Bt^T); col-chunk sums -> part ----------
// 128x128 tile, BK=64, 256 thr (4 waves, 2x2 of 64x64), XOR-swizzled LDS (32 KB).
__global__ __launch_bounds__(256, 2)
void gemm_exp(const unsigned short* __restrict__ A,
              const unsigned short* __restrict__ Bt,
              unsigned char* __restrict__ C8,
              float* __restrict__ part,
              int K, int N) {
  __shared__ short lA[128*64];
  __shared__ short lB[128*64];
  const int tid  = threadIdx.x;
  const int lane = tid & 63;
  const int wm   = (tid >> 6) >> 1, wn = (tid >> 6) & 1;
  const int rowBase = blockIdx.y * 128;
  const int colBase = blockIdx.x * 128;

  v4f acc[4][4];
  #pragma unroll
  for (int i=0;i<4;++i)
    #pragma unroll
    for (int j=0;j<4;++j) acc[i][j] = (v4f){0.f,0.f,0.f,0.f};

  for (int k0 = 0; k0 < K; k0 += 64) {
    #pragma unroll
    for (int j = 0; j < 4; ++j) {
      int s = j*256 + tid;
      int m = s >> 3;
      int c = (s & 7) ^ (m & 7);
      g2l16(A + (size_t)(rowBase + m)*K + k0 + c*8, &lA[s*8]);
    }
    #pragma unroll
    for (int j = 0; j < 4; ++j) {
      int s = j*256 + tid;
      int m = s >> 3;
      int c = (s & 7) ^ (m & 7);
      g2l16(Bt + (size_t)(colBase + m)*K + k0 + c*8, &lB[s*8]);
    }
    __syncthreads();
    #pragma unroll
    for (int s2 = 0; s2 < 2; ++s2) {
      const int quad = lane >> 4;
      const int cc = s2*4 + quad;
      short8 aF[4], bF[4];
      #pragma unroll
      for (int mt = 0; mt < 4; ++mt) {
        int ml = wm*64 + mt*16 + (lane & 15);
        aF[mt] = *(const short8*)&lA[(ml*8 + (cc ^ (ml & 7)))*8];
      }
      #pragma unroll
      for (int nt = 0; nt < 4; ++nt) {
        int nl = wn*64 + nt*16 + (lane & 15);
        bF[nt] = *(const short8*)&lB[(nl*8 + (cc ^ (nl & 7)))*8];
      }
      #pragma unroll
      for (int mt = 0; mt < 4; ++mt)
        #pragma unroll
        for (int nt = 0; nt < 4; ++nt)
          acc[mt][nt] = __builtin_amdgcn_mfma_f32_16x16x32_bf16(aF[mt], bF[nt], acc[mt][nt], 0, 0, 0);
    }
    __syncthreads();
  }

  const int quad = lane >> 4, c15 = lane & 15;
  float csum[4] = {0.f, 0.f, 0.f, 0.f};
  #pragma unroll
  for (int mt = 0; mt < 4; ++mt) {
    #pragma unroll
    for (int nt = 0; nt < 4; ++nt) {
      int col = colBase + wn*64 + nt*16 + c15;
      #pragma unroll
      for (int r = 0; r < 4; ++r) {
        int row = rowBase + wm*64 + mt*16 + quad*4 + r;
        size_t idx = (size_t)row*N + col;
        float e = __expf(acc[mt][nt][r]);
        C8[idx] = f2e4m3(e);
        csum[nt] += e;
      }
    }
  }
  // epilogue column sums; cs reuses lA (dead after final barrier above)
  float* cs = (float*)lA;   // [2][128]
  #pragma unroll
  for (int nt = 0; nt < 4; ++nt) {
    float s = csum[nt];
    s += __shfl_xor(s, 16, 64);
    s += __shfl_xor(s, 32, 64);
    if (lane < 16) cs[wm*128 + wn*64 + nt*16 + lane] = s;
  }
  __syncthreads();
  if (tid < 128)
    part[(size_t)(colBase + tid)*64 + blockIdx.y] = cs[tid] + cs[128 + tid];
}

// ---------- GEMM2: Ph[z][row][col] = (fp16) A*Bt^T partial, split-K ----------
__global__ __launch_bounds__(256, 2)
void gemm_out(const unsigned short* __restrict__ A,
              const unsigned short* __restrict__ Bt,
              unsigned short* __restrict__ Ph,
              int K, int KCH, int N) {
  __shared__ short lA[128*64];
  __shared__ short lB[128*64];
  const int tid  = threadIdx.x;
  const int lane = tid & 63;
  const int wm   = (tid >> 6) >> 1, wn = (tid >> 6) & 1;
  const int rowBase = blockIdx.y * 128;
  const int colBase = blockIdx.x * 128;
  const int kStart  = blockIdx.z * KCH;

  v4f acc[4][4];
  #pragma unroll
  for (int i=0;i<4;++i)
    #pragma unroll
    for (int j=0;j<4;++j) acc[i][j] = (v4f){0.f,0.f,0.f,0.f};

  for (int k0 = kStart; k0 < kStart + KCH; k0 += 64) {
    #pragma unroll
    for (int j = 0; j < 4; ++j) {
      int s = j*256 + tid;
      int m = s >> 3;
      int c = (s & 7) ^ (m & 7);
      g2l16(A + (size_t)(rowBase + m)*K + k0 + c*8, &lA[s*8]);
    }
    #pragma unroll
    for (int j = 0; j < 4; ++j) {
      int s = j*256 + tid;
      int m = s >> 3;
      int c = (s & 7) ^ (m & 7);
      g2l16(Bt + (size_t)(colBase + m)*K + k0 + c*8, &lB[s*8]);
    }
    __syncthreads();
    #pragma unroll
    for (int s2 = 0; s2 < 2; ++s2) {
      const int quad = lane >> 4;
      const int cc = s2*4 + quad;
      short8 aF[4], bF[4];
      #pragma unroll
      for (int mt = 0; mt < 4; ++mt) {
        int ml = wm*64 + mt*16 + (lane & 15);
        aF[mt] = *(const short8*)&lA[(ml*8 + (cc ^ (ml & 7)))*8];
      }
      #pragma unroll
      for (int nt = 0; nt < 4; ++nt) {
        int nl = wn*64 + nt*16 + (lane & 15);
        bF[nt] = *(const short8*)&lB[(nl*8 + (cc ^ (nl & 7)))*8];
      }
      #pragma unroll
      for (int mt = 0; mt < 4; ++mt)
        #pragma unroll
        for (int nt = 0; nt < 4; ++nt)
          acc[mt][nt] = __builtin_amdgcn_mfma_f32_16x16x32_bf16(aF[mt], bF[nt], acc[mt][nt], 0, 0, 0);
    }
    __syncthreads();
  }

  const int quad = lane >> 4, c15 = lane & 15;
  #pragma unroll
  for (int mt = 0; mt < 4; ++mt) {
    #pragma unroll
    for (int nt = 0; nt < 4; ++nt) {
      int col = colBase + wn*64 + nt*16 + c15;
      #pragma unroll
      for (int r = 0; r < 4; ++r) {
        int row = rowBase + wm*64 + mt*16 + quad*4 + r;
        size_t idx = ((size_t)blockIdx.z*MROWS + row)*N + col;
        _Float16 h = (_Float16)acc[mt][nt][r];
        Ph[idx] = *(unsigned short*)&h;
      }
    }
  }
}

// ---------- exclusive prefix over 32 chunks per (col, batch) ----------
__global__ __launch_bounds__(256) void scan_prefix(float* __restrict__ part) {
  int idx = blockIdx.x*256 + threadIdx.x;   // 0..16383
  int col = idx >> 1, bb = idx & 1;
  float* p = part + (size_t)col*64 + bb*NCH;
  float run = 0.f;
  #pragma unroll
  for (int c = 0; c < NCH; ++c) { float v = p[c]; p[c] = run; run += v; }
}

// ---------- emit y = Sa*Sb/t^2 (bf16) from fp8 exp values ----------
__global__ __launch_bounds__(256) void scan_emit(const unsigned char* __restrict__ ab,
                                                 const float* __restrict__ part,
                                                 unsigned short* __restrict__ y) {
  int h = blockIdx.x*256 + threadIdx.x;     // 0..4095
  int cy = blockIdx.y, bb = blockIdx.z;
  float sa = part[(size_t)h*64 + bb*NCH + cy];
  float sb = part[(size_t)(HID + h)*64 + bb*NCH + cy];
  const unsigned char* pa = ab + ((size_t)(bb*TT + cy*CHUNK))*N1 + h;
  const unsigned char* pb = pa + HID;
  unsigned short* py = y + ((size_t)(bb*TT + cy*CHUNK))*HID + h;
  int t0 = cy*CHUNK;
  #pragma unroll 4
  for (int i = 0; i < CHUNK; ++i) {
    sa += e4m32f(pa[(size_t)i*N1]);
    sb += e4m32f(pb[(size_t)i*N1]);
    float inv = 1.0f / (float)(t0 + i + 1);
    py[(size_t)i*HID] = f2bf(sa*sb*inv*inv);
  }
}

// ---------- out = x + Sc[row]*sum_z partial_z (fp16 partials) ----------
__global__ __launch_bounds__(256) void reduce_out(const unsigned short* __restrict__ p,
                                                  const float* __restrict__ x,
                                                  const float* __restrict__ Sc,
                                                  float* __restrict__ o) {
  size_t i = ((size_t)blockIdx.x*256 + threadIdx.x)*4;
  int row = (int)(i >> 10);   // EMB = 1024 elements per row
  float4 xv = *(const float4*)(x + i);
  float s0 = 0.f, s1 = 0.f, s2 = 0.f, s3 = 0.f;
  #pragma unroll
  for (int z = 0; z < 4; ++z) {
    ushort4 u = *(const ushort4*)(p + (size_t)z*MROWS*EMB + i);
    s0 += h2f(u.x); s1 += h2f(u.y); s2 += h2f(u.z); s3 += h2f(u.w);
  }
  float sc = Sc[row];
  float4 ov; ov.x = xv.x + sc*s0; ov.y = xv.y + sc*s1; ov.z = xv.z + sc*s2; ov.w = xv.w + sc*s3;
  *(float4*)(o + i) = ov;
}

extern "C" void kernel_launch(void* const* d_in, const int* in_sizes, int n_in,
                              void* d_out, int out_size, void* d_ws, size_t ws_size,
                              hipStream_t stream) {
  const float* x  = (const float*)d_in[0];
  const float* W1 = (const float*)d_in[1];
  const float* W2 = (const float*)d_in[2];
  const float* W3 = (const float*)d_in[3];
  float* out = (float*)d_out;
  char* ws = (char*)d_ws;

  unsigned short* r_bf   = (unsigned short*)(ws);                 // 16 MB
  unsigned short* w12_bf = (unsigned short*)(ws + 16777216ull);   // 16 MB
  unsigned short* w3_bf  = (unsigned short*)(ws + 33554432ull);   // 8 MB
  unsigned char*  ab8    = (unsigned char*) (ws + 41943040ull);   // 64 MiB fp8
  unsigned short* y_bf   = (unsigned short*)(ws + 109051904ull);  // 64 MiB
  float*          sc     = (float*)(ws + 176160768ull);           // 32 KB
  // psum (4 x 16.78 MB fp16 GEMM2 partials) reuses dead ab8 (exactly 64 MiB)
  unsigned short* psum   = (unsigned short*)ab8;
  // part (per-chunk column sums) lives in d_out; dead before reduce_out
  float*          part   = (float*)d_out;                         // 2 MB

  conv_all<<<12288, 256, 0, stream>>>(W1, W2, W3, w12_bf, w3_bf);
  rmsnorm_x<<<MROWS, 256, 0, stream>>>(x, r_bf);
  gemm_exp<<<dim3(64,64), 256, 0, stream>>>(r_bf, w12_bf, ab8, part, EMB, N1);
  scan_prefix<<<64, 256, 0, stream>>>(part);
  scan_emit<<<dim3(16,NCH,2), 256, 0, stream>>>(ab8, part, y_bf);
  rowssq<<<MROWS, 256, 0, stream>>>(y_bf, sc);
  gemm_out<<<dim3(8,64,4), 256, 0, stream>>>(y_bf, w3_bf, psum, HID, 1024, EMB);
  reduce_out<<<8192, 256, 0, stream>>>(psum, x, sc, out);
}

// Round 9
// 389.742 us; speedup vs baseline: 1.1372x; 1.0446x over previous
//
#include <hip/hip_runtime.h>
#include <hip/hip_fp8.h>

#define EMB 1024
#define HID 4096
#define NB 2
#define TT 4096
#define MROWS (NB*TT)   // 8192
#define N1 (2*HID)      // 8192
#define CHUNK 128       // = GEMM1 row tile
#define NCH 32          // chunks per batch (TT/CHUNK)

typedef short short8 __attribute__((ext_vector_type(8)));
typedef float v4f   __attribute__((ext_vector_type(4)));

__device__ __forceinline__ unsigned short f2bf(float f) {
  unsigned int u = __float_as_uint(f);
  u += 0x7FFFu + ((u >> 16) & 1u);
  return (unsigned short)(u >> 16);
}
__device__ __forceinline__ float bf2f(unsigned short s) {
  return __uint_as_float(((unsigned int)s) << 16);
}
__device__ __forceinline__ float h2f(unsigned short u) {
  return (float)(*(const _Float16*)&u);
}
__device__ __forceinline__ unsigned char f2e4m3(float f) {
  __hip_fp8_e4m3 q(f);
  return *(unsigned char*)&q;
}
__device__ __forceinline__ float e4m32f(unsigned char c) {
  __hip_fp8_e4m3 q = *(__hip_fp8_e4m3*)&c;
  return (float)q;
}
__device__ __forceinline__ void g2l16(const void* g, void* l) {
  __builtin_amdgcn_global_load_lds(
      (const __attribute__((address_space(1))) void*)g,
      (__attribute__((address_space(3))) void*)l, 16, 0, 0);
}

__device__ __forceinline__ float block_reduce_sum(float v, float* sbuf) {
  #pragma unroll
  for (int off = 32; off; off >>= 1) v += __shfl_down(v, off, 64);
  int lane = threadIdx.x & 63, w = threadIdx.x >> 6;
  if (lane == 0) sbuf[w] = v;
  __syncthreads();
  return sbuf[0] + sbuf[1] + sbuf[2] + sbuf[3];
}

// ---------- merged weight convert: W1|W2 -> bf16, W3 -> fp8 x64 ----------
__global__ __launch_bounds__(256) void conv_all(const float* __restrict__ W1,
                                                const float* __restrict__ W2,
                                                const float* __restrict__ W3,
                                                unsigned short* __restrict__ o12,
                                                unsigned char* __restrict__ o3) {
  size_t i = ((size_t)blockIdx.x*256 + threadIdx.x)*4;
  if (i < 2ull*HID*EMB) {
    const float* s = (i < (size_t)HID*EMB) ? (W1 + i) : (W2 + (i - (size_t)HID*EMB));
    float4 v = *(const float4*)s;
    ushort4 u; u.x=f2bf(v.x); u.y=f2bf(v.y); u.z=f2bf(v.z); u.w=f2bf(v.w);
    *(ushort4*)(o12 + i) = u;
  } else {
    size_t off = i - 2ull*HID*EMB;
    float4 v = *(const float4*)(W3 + off);
    uchar4 u; u.x=f2e4m3(v.x*64.f); u.y=f2e4m3(v.y*64.f);
             u.z=f2e4m3(v.z*64.f); u.w=f2e4m3(v.w*64.f);
    *(uchar4*)(o3 + off) = u;
  }
}

// ---------- rmsnorm (fp32 in, bf16 out), row = EMB ----------
__global__ __launch_bounds__(256) void rmsnorm_x(const float* __restrict__ x,
                                                 unsigned short* __restrict__ r) {
  __shared__ float sbuf[4];
  int row = blockIdx.x;
  float4 v = *(const float4*)(x + (size_t)row*EMB + threadIdx.x*4);
  float ss = v.x*v.x + v.y*v.y + v.z*v.z + v.w*v.w;
  float tot = block_reduce_sum(ss, sbuf);
  float sc = rsqrtf(tot * (1.0f/EMB) + 1e-6f);
  ushort4 o; o.x=f2bf(v.x*sc); o.y=f2bf(v.y*sc); o.z=f2bf(v.z*sc); o.w=f2bf(v.w*sc);
  *(ushort4*)(r + (size_t)row*EMB + threadIdx.x*4) = o;
}

// ---------- normalize + quantize: y8 = fp8(y * rsqrt(mean(y^2)+eps)) ----------
__global__ __launch_bounds__(256) void normq(const unsigned short* __restrict__ y,
                                             unsigned char* __restrict__ y8) {
  __shared__ float sbuf[4];
  int row = blockIdx.x;
  const unsigned short* p = y + (size_t)row*HID + threadIdx.x*16;
  short8 v0 = *(const short8*)p;
  short8 v1 = *(const short8*)(p+8);
  float f[16]; float ss = 0.f;
  #pragma unroll
  for (int j=0;j<8;++j){ f[j]=bf2f((unsigned short)v0[j]); f[j+8]=bf2f((unsigned short)v1[j]); }
  #pragma unroll
  for (int j=0;j<16;++j) ss += f[j]*f[j];
  float tot = block_reduce_sum(ss, sbuf);
  float sc = rsqrtf(tot*(1.0f/HID) + 1e-6f);
  unsigned int w[4];
  #pragma unroll
  for (int g=0; g<4; ++g) {
    unsigned int a0 = f2e4m3(f[g*4+0]*sc);
    unsigned int a1 = f2e4m3(f[g*4+1]*sc);
    unsigned int a2 = f2e4m3(f[g*4+2]*sc);
    unsigned int a3 = f2e4m3(f[g*4+3]*sc);
    w[g] = a0 | (a1<<8) | (a2<<16) | (a3<<24);
  }
  uint4 o; o.x=w[0]; o.y=w[1]; o.z=w[2]; o.w=w[3];
  *(uint4*)(y8 + (size_t)row*HID + threadIdx.x*16) = o;
}

// ---------- GEMM1: C8 = (fp8 e4m3) exp(A*Bt^T); col-chunk sums -> part ----------
// bf16 MFMA, 128x128 tile, BK=64, XOR-swizzled LDS (32 KB).
__global__ __launch_bounds__(256, 2)
void gemm_exp(const unsigned short* __restrict__ A,
              const unsigned short* __restrict__ Bt,
              unsigned char* __restrict__ C8,
              float* __restrict__ part,
              int K, int N) {
  __shared__ short lA[128*64];
  __shared__ short lB[128*64];
  const int tid  = threadIdx.x;
  const int lane = tid & 63;
  const int wm   = (tid >> 6) >> 1, wn = (tid >> 6) & 1;
  const int rowBase = blockIdx.y * 128;
  const int colBase = blockIdx.x * 128;

  v4f acc[4][4];
  #pragma unroll
  for (int i=0;i<4;++i)
    #pragma unroll
    for (int j=0;j<4;++j) acc[i][j] = (v4f){0.f,0.f,0.f,0.f};

  for (int k0 = 0; k0 < K; k0 += 64) {
    #pragma unroll
    for (int j = 0; j < 4; ++j) {
      int s = j*256 + tid;
      int m = s >> 3;
      int c = (s & 7) ^ (m & 7);
      g2l16(A + (size_t)(rowBase + m)*K + k0 + c*8, &lA[s*8]);
    }
    #pragma unroll
    for (int j = 0; j < 4; ++j) {
      int s = j*256 + tid;
      int m = s >> 3;
      int c = (s & 7) ^ (m & 7);
      g2l16(Bt + (size_t)(colBase + m)*K + k0 + c*8, &lB[s*8]);
    }
    __syncthreads();
    #pragma unroll
    for (int s2 = 0; s2 < 2; ++s2) {
      const int quad = lane >> 4;
      const int cc = s2*4 + quad;
      short8 aF[4], bF[4];
      #pragma unroll
      for (int mt = 0; mt < 4; ++mt) {
        int ml = wm*64 + mt*16 + (lane & 15);
        aF[mt] = *(const short8*)&lA[(ml*8 + (cc ^ (ml & 7)))*8];
      }
      #pragma unroll
      for (int nt = 0; nt < 4; ++nt) {
        int nl = wn*64 + nt*16 + (lane & 15);
        bF[nt] = *(const short8*)&lB[(nl*8 + (cc ^ (nl & 7)))*8];
      }
      #pragma unroll
      for (int mt = 0; mt < 4; ++mt)
        #pragma unroll
        for (int nt = 0; nt < 4; ++nt)
          acc[mt][nt] = __builtin_amdgcn_mfma_f32_16x16x32_bf16(aF[mt], bF[nt], acc[mt][nt], 0, 0, 0);
    }
    __syncthreads();
  }

  const int quad = lane >> 4, c15 = lane & 15;
  float csum[4] = {0.f, 0.f, 0.f, 0.f};
  #pragma unroll
  for (int mt = 0; mt < 4; ++mt) {
    #pragma unroll
    for (int nt = 0; nt < 4; ++nt) {
      int col = colBase + wn*64 + nt*16 + c15;
      #pragma unroll
      for (int r = 0; r < 4; ++r) {
        int row = rowBase + wm*64 + mt*16 + quad*4 + r;
        size_t idx = (size_t)row*N + col;
        float e = __expf(acc[mt][nt][r]);
        C8[idx] = f2e4m3(e);
        csum[nt] += e;
      }
    }
  }
  float* cs = (float*)lA;   // [2][128], reuses dead lA
  #pragma unroll
  for (int nt = 0; nt < 4; ++nt) {
    float s = csum[nt];
    s += __shfl_xor(s, 16, 64);
    s += __shfl_xor(s, 32, 64);
    if (lane < 16) cs[wm*128 + wn*64 + nt*16 + lane] = s;
  }
  __syncthreads();
  if (tid < 128)
    part[(size_t)(colBase + tid)*64 + blockIdx.y] = cs[tid] + cs[128 + tid];
}

// ---------- GEMM2 (fp8): Ph[z] = (fp16) yhat8 * (w3*64)^T, split-K ----------
// 128x128 tile, BK=128 fp8, 16+16 KB LDS, XOR-swizzled 16B chunks.
__global__ __launch_bounds__(256, 2)
void gemm_out(const unsigned char* __restrict__ A8,
              const unsigned char* __restrict__ B8,
              unsigned short* __restrict__ Ph,
              int K, int KCH, int N) {
  __shared__ unsigned char lA8[128*128];
  __shared__ unsigned char lB8[128*128];
  const int tid  = threadIdx.x;
  const int lane = tid & 63;
  const int wm   = (tid >> 6) >> 1, wn = (tid >> 6) & 1;
  const int rowBase = blockIdx.y * 128;
  const int colBase = blockIdx.x * 128;
  const int kStart  = blockIdx.z * KCH;

  v4f acc[4][4];
  #pragma unroll
  for (int i=0;i<4;++i)
    #pragma unroll
    for (int j=0;j<4;++j) acc[i][j] = (v4f){0.f,0.f,0.f,0.f};

  for (int k0 = kStart; k0 < kStart + KCH; k0 += 128) {
    // stage: 1024 slots/tile, slot s = (row m = s>>3, phys 16B-chunk p = s&7)
    // holding logical chunk c = p ^ (m&7)
    #pragma unroll
    for (int j = 0; j < 4; ++j) {
      int s = j*256 + tid;
      int m = s >> 3;
      int c = (s & 7) ^ (m & 7);
      g2l16(A8 + (size_t)(rowBase + m)*K + k0 + c*16, &lA8[s*16]);
    }
    #pragma unroll
    for (int j = 0; j < 4; ++j) {
      int s = j*256 + tid;
      int m = s >> 3;
      int c = (s & 7) ^ (m & 7);
      g2l16(B8 + (size_t)(colBase + m)*K + k0 + c*16, &lB8[s*16]);
    }
    __syncthreads();
    #pragma unroll
    for (int s2 = 0; s2 < 4; ++s2) {
      const int quad = lane >> 4;
      // lane needs 8 fp8 at k_local = s2*32 + quad*8
      const int cc = s2*2 + (quad >> 1);   // logical 16B chunk
      const int hh = quad & 1;             // 8B half within chunk
      long aF[4], bF[4];
      #pragma unroll
      for (int mt = 0; mt < 4; ++mt) {
        int ml = wm*64 + mt*16 + (lane & 15);
        aF[mt] = *(const long*)&lA8[ml*128 + ((cc ^ (ml & 7))<<4) + (hh<<3)];
      }
      #pragma unroll
      for (int nt = 0; nt < 4; ++nt) {
        int nl = wn*64 + nt*16 + (lane & 15);
        bF[nt] = *(const long*)&lB8[nl*128 + ((cc ^ (nl & 7))<<4) + (hh<<3)];
      }
      #pragma unroll
      for (int mt = 0; mt < 4; ++mt)
        #pragma unroll
        for (int nt = 0; nt < 4; ++nt)
          acc[mt][nt] = __builtin_amdgcn_mfma_f32_16x16x32_fp8_fp8(aF[mt], bF[nt], acc[mt][nt], 0, 0, 0);
    }
    __syncthreads();
  }

  const int quad = lane >> 4, c15 = lane & 15;
  #pragma unroll
  for (int mt = 0; mt < 4; ++mt) {
    #pragma unroll
    for (int nt = 0; nt < 4; ++nt) {
      int col = colBase + wn*64 + nt*16 + c15;
      #pragma unroll
      for (int r = 0; r < 4; ++r) {
        int row = rowBase + wm*64 + mt*16 + quad*4 + r;
        size_t idx = ((size_t)blockIdx.z*MROWS + row)*N + col;
        _Float16 h = (_Float16)acc[mt][nt][r];
        Ph[idx] = *(unsigned short*)&h;
      }
    }
  }
}

// ---------- exclusive prefix over 32 chunks per (col, batch) ----------
__global__ __launch_bounds__(256) void scan_prefix(float* __restrict__ part) {
  int idx = blockIdx.x*256 + threadIdx.x;   // 0..16383
  int col = idx >> 1, bb = idx & 1;
  float* p = part + (size_t)col*64 + bb*NCH;
  float run = 0.f;
  #pragma unroll
  for (int c = 0; c < NCH; ++c) { float v = p[c]; p[c] = run; run += v; }
}

// ---------- emit y = Sa*Sb/t^2 (bf16) from fp8 exp values ----------
__global__ __launch_bounds__(256) void scan_emit(const unsigned char* __restrict__ ab,
                                                 const float* __restrict__ part,
                                                 unsigned short* __restrict__ y) {
  int h = blockIdx.x*256 + threadIdx.x;     // 0..4095
  int cy = blockIdx.y, bb = blockIdx.z;
  float sa = part[(size_t)h*64 + bb*NCH + cy];
  float sb = part[(size_t)(HID + h)*64 + bb*NCH + cy];
  const unsigned char* pa = ab + ((size_t)(bb*TT + cy*CHUNK))*N1 + h;
  const unsigned char* pb = pa + HID;
  unsigned short* py = y + ((size_t)(bb*TT + cy*CHUNK))*HID + h;
  int t0 = cy*CHUNK;
  #pragma unroll 4
  for (int i = 0; i < CHUNK; ++i) {
    sa += e4m32f(pa[(size_t)i*N1]);
    sb += e4m32f(pb[(size_t)i*N1]);
    float inv = 1.0f / (float)(t0 + i + 1);
    py[(size_t)i*HID] = f2bf(sa*sb*inv*inv);
  }
}

// ---------- out = x + (1/64)*sum_z partial_z (fp16 partials) ----------
__global__ __launch_bounds__(256) void reduce_out(const unsigned short* __restrict__ p,
                                                  const float* __restrict__ x,
                                                  float* __restrict__ o) {
  size_t i = ((size_t)blockIdx.x*256 + threadIdx.x)*4;
  float4 xv = *(const float4*)(x + i);
  float s0 = 0.f, s1 = 0.f, s2 = 0.f, s3 = 0.f;
  #pragma unroll
  for (int z = 0; z < 4; ++z) {
    ushort4 u = *(const ushort4*)(p + (size_t)z*MROWS*EMB + i);
    s0 += h2f(u.x); s1 += h2f(u.y); s2 += h2f(u.z); s3 += h2f(u.w);
  }
  const float inv64 = 1.0f/64.0f;
  float4 ov; ov.x = xv.x + inv64*s0; ov.y = xv.y + inv64*s1;
             ov.z = xv.z + inv64*s2; ov.w = xv.w + inv64*s3;
  *(float4*)(o + i) = ov;
}

extern "C" void kernel_launch(void* const* d_in, const int* in_sizes, int n_in,
                              void* d_out, int out_size, void* d_ws, size_t ws_size,
                              hipStream_t stream) {
  const float* x  = (const float*)d_in[0];
  const float* W1 = (const float*)d_in[1];
  const float* W2 = (const float*)d_in[2];
  const float* W3 = (const float*)d_in[3];
  float* out = (float*)d_out;
  char* ws = (char*)d_ws;

  unsigned short* r_bf   = (unsigned short*)(ws);                 // 16 MiB
  unsigned short* w12_bf = (unsigned short*)(ws + 16777216ull);   // 16 MiB
  unsigned char*  w3_8   = (unsigned char*) (ws + 33554432ull);   // 4 MiB fp8 (x64)
  unsigned char*  ab8    = (unsigned char*) (ws + 37748736ull);   // 64 MiB fp8
  unsigned short* y_bf   = (unsigned short*)(ws + 104857600ull);  // 64 MiB
  unsigned char*  y8     = (unsigned char*) (ws + 171966464ull);  // 32 MiB fp8 (normalized)
  // psum (4 x 16 MiB fp16 GEMM2 partials) reuses dead ab8 (exactly 64 MiB)
  unsigned short* psum   = (unsigned short*)ab8;
  // part (per-chunk column sums) lives in d_out; dead before reduce_out
  float*          part   = (float*)d_out;                         // 2 MB

  conv_all<<<12288, 256, 0, stream>>>(W1, W2, W3, w12_bf, w3_8);
  rmsnorm_x<<<MROWS, 256, 0, stream>>>(x, r_bf);
  gemm_exp<<<dim3(64,64), 256, 0, stream>>>(r_bf, w12_bf, ab8, part, EMB, N1);
  scan_prefix<<<64, 256, 0, stream>>>(part);
  scan_emit<<<dim3(16,NCH,2), 256, 0, stream>>>(ab8, part, y_bf);
  normq<<<MROWS, 256, 0, stream>>>(y_bf, y8);
  gemm_out<<<dim3(8,64,4), 256, 0, stream>>>(y8, w3_8, psum, HID, 1024, EMB);
  reduce_out<<<8192, 256, 0, stream>>>(psum, x, out);
}

// Round 10
// 379.926 us; speedup vs baseline: 1.1666x; 1.0258x over previous
//
#include <hip/hip_runtime.h>
#include <hip/hip_fp8.h>

#define EMB 1024
#define HID 4096
#define NB 2
#define TT 4096
#define MROWS (NB*TT)   // 8192
#define N1 (2*HID)      // 8192
#define CHUNK 128       // = GEMM1 row tile
#define NCH 32          // chunks per batch (TT/CHUNK)

typedef short short8 __attribute__((ext_vector_type(8)));
typedef float v4f   __attribute__((ext_vector_type(4)));

__device__ __forceinline__ unsigned short f2bf(float f) {
  unsigned int u = __float_as_uint(f);
  u += 0x7FFFu + ((u >> 16) & 1u);
  return (unsigned short)(u >> 16);
}
__device__ __forceinline__ float bf2f(unsigned short s) {
  return __uint_as_float(((unsigned int)s) << 16);
}
__device__ __forceinline__ float h2f(unsigned short u) {
  return (float)(*(const _Float16*)&u);
}
__device__ __forceinline__ unsigned char f2e4m3(float f) {
  __hip_fp8_e4m3 q(f);
  return *(unsigned char*)&q;
}
__device__ __forceinline__ float e4m32f(unsigned char c) {
  __hip_fp8_e4m3 q = *(__hip_fp8_e4m3*)&c;
  return (float)q;
}
__device__ __forceinline__ void g2l16(const void* g, void* l) {
  __builtin_amdgcn_global_load_lds(
      (const __attribute__((address_space(1))) void*)g,
      (__attribute__((address_space(3))) void*)l, 16, 0, 0);
}

__device__ __forceinline__ float block_reduce_sum(float v, float* sbuf) {
  #pragma unroll
  for (int off = 32; off; off >>= 1) v += __shfl_down(v, off, 64);
  int lane = threadIdx.x & 63, w = threadIdx.x >> 6;
  if (lane == 0) sbuf[w] = v;
  __syncthreads();
  return sbuf[0] + sbuf[1] + sbuf[2] + sbuf[3];
}

// ---------- merged weight convert: W1|W2 -> bf16, W3 -> fp8 x64 ----------
__global__ __launch_bounds__(256) void conv_all(const float* __restrict__ W1,
                                                const float* __restrict__ W2,
                                                const float* __restrict__ W3,
                                                unsigned short* __restrict__ o12,
                                                unsigned char* __restrict__ o3) {
  size_t i = ((size_t)blockIdx.x*256 + threadIdx.x)*4;
  if (i < 2ull*HID*EMB) {
    const float* s = (i < (size_t)HID*EMB) ? (W1 + i) : (W2 + (i - (size_t)HID*EMB));
    float4 v = *(const float4*)s;
    ushort4 u; u.x=f2bf(v.x); u.y=f2bf(v.y); u.z=f2bf(v.z); u.w=f2bf(v.w);
    *(ushort4*)(o12 + i) = u;
  } else {
    size_t off = i - 2ull*HID*EMB;
    float4 v = *(const float4*)(W3 + off);
    uchar4 u; u.x=f2e4m3(v.x*64.f); u.y=f2e4m3(v.y*64.f);
             u.z=f2e4m3(v.z*64.f); u.w=f2e4m3(v.w*64.f);
    *(uchar4*)(o3 + off) = u;
  }
}

// ---------- rmsnorm (fp32 in, bf16 out), row = EMB ----------
__global__ __launch_bounds__(256) void rmsnorm_x(const float* __restrict__ x,
                                                 unsigned short* __restrict__ r) {
  __shared__ float sbuf[4];
  int row = blockIdx.x;
  float4 v = *(const float4*)(x + (size_t)row*EMB + threadIdx.x*4);
  float ss = v.x*v.x + v.y*v.y + v.z*v.z + v.w*v.w;
  float tot = block_reduce_sum(ss, sbuf);
  float sc = rsqrtf(tot * (1.0f/EMB) + 1e-6f);
  ushort4 o; o.x=f2bf(v.x*sc); o.y=f2bf(v.y*sc); o.z=f2bf(v.z*sc); o.w=f2bf(v.w*sc);
  *(ushort4*)(r + (size_t)row*EMB + threadIdx.x*4) = o;
}

// ---------- normalize + quantize: y8 = fp8(y * rsqrt(mean(y^2)+eps)) ----------
__global__ __launch_bounds__(256) void normq(const unsigned short* __restrict__ y,
                                             unsigned char* __restrict__ y8) {
  __shared__ float sbuf[4];
  int row = blockIdx.x;
  const unsigned short* p = y + (size_t)row*HID + threadIdx.x*16;
  short8 v0 = *(const short8*)p;
  short8 v1 = *(const short8*)(p+8);
  float f[16]; float ss = 0.f;
  #pragma unroll
  for (int j=0;j<8;++j){ f[j]=bf2f((unsigned short)v0[j]); f[j+8]=bf2f((unsigned short)v1[j]); }
  #pragma unroll
  for (int j=0;j<16;++j) ss += f[j]*f[j];
  float tot = block_reduce_sum(ss, sbuf);
  float sc = rsqrtf(tot*(1.0f/HID) + 1e-6f);
  unsigned int w[4];
  #pragma unroll
  for (int g=0; g<4; ++g) {
    unsigned int a0 = f2e4m3(f[g*4+0]*sc);
    unsigned int a1 = f2e4m3(f[g*4+1]*sc);
    unsigned int a2 = f2e4m3(f[g*4+2]*sc);
    unsigned int a3 = f2e4m3(f[g*4+3]*sc);
    w[g] = a0 | (a1<<8) | (a2<<16) | (a3<<24);
  }
  uint4 o; o.x=w[0]; o.y=w[1]; o.z=w[2]; o.w=w[3];
  *(uint4*)(y8 + (size_t)row*HID + threadIdx.x*16) = o;
}

// ---------- GEMM1: C8 = (fp8 e4m3) exp(A*Bt^T); col-chunk sums -> part ----------
// bf16 MFMA, 128x128 tile, BK=64, XOR-swizzled LDS (32 KB).
// XCD-aware swizzle: 1D grid 4096; xcd = bid&7 owns col-stripe [xcd*8, xcd*8+8);
// within stripe, cols cycle fastest so the A row-tile is reused 8x while L2-hot.
__global__ __launch_bounds__(256, 2)
void gemm_exp(const unsigned short* __restrict__ A,
              const unsigned short* __restrict__ Bt,
              unsigned char* __restrict__ C8,
              float* __restrict__ part,
              int K, int N) {
  __shared__ short lA[128*64];
  __shared__ short lB[128*64];
  const int tid  = threadIdx.x;
  const int lane = tid & 63;
  const int wm   = (tid >> 6) >> 1, wn = (tid >> 6) & 1;
  const int bid  = blockIdx.x;
  const int s0i  = bid >> 3;
  const int rowTile = s0i >> 3;                       // 0..63
  const int colTile = ((bid & 7) << 3) | (s0i & 7);   // 0..63
  const int rowBase = rowTile * 128;
  const int colBase = colTile * 128;

  v4f acc[4][4];
  #pragma unroll
  for (int i=0;i<4;++i)
    #pragma unroll
    for (int j=0;j<4;++j) acc[i][j] = (v4f){0.f,0.f,0.f,0.f};

  for (int k0 = 0; k0 < K; k0 += 64) {
    #pragma unroll
    for (int j = 0; j < 4; ++j) {
      int s = j*256 + tid;
      int m = s >> 3;
      int c = (s & 7) ^ (m & 7);
      g2l16(A + (size_t)(rowBase + m)*K + k0 + c*8, &lA[s*8]);
    }
    #pragma unroll
    for (int j = 0; j < 4; ++j) {
      int s = j*256 + tid;
      int m = s >> 3;
      int c = (s & 7) ^ (m & 7);
      g2l16(Bt + (size_t)(colBase + m)*K + k0 + c*8, &lB[s*8]);
    }
    __syncthreads();
    #pragma unroll
    for (int s2 = 0; s2 < 2; ++s2) {
      const int quad = lane >> 4;
      const int cc = s2*4 + quad;
      short8 aF[4], bF[4];
      #pragma unroll
      for (int mt = 0; mt < 4; ++mt) {
        int ml = wm*64 + mt*16 + (lane & 15);
        aF[mt] = *(const short8*)&lA[(ml*8 + (cc ^ (ml & 7)))*8];
      }
      #pragma unroll
      for (int nt = 0; nt < 4; ++nt) {
        int nl = wn*64 + nt*16 + (lane & 15);
        bF[nt] = *(const short8*)&lB[(nl*8 + (cc ^ (nl & 7)))*8];
      }
      #pragma unroll
      for (int mt = 0; mt < 4; ++mt)
        #pragma unroll
        for (int nt = 0; nt < 4; ++nt)
          acc[mt][nt] = __builtin_amdgcn_mfma_f32_16x16x32_bf16(aF[mt], bF[nt], acc[mt][nt], 0, 0, 0);
    }
    __syncthreads();
  }

  const int quad = lane >> 4, c15 = lane & 15;
  float csum[4] = {0.f, 0.f, 0.f, 0.f};
  #pragma unroll
  for (int mt = 0; mt < 4; ++mt) {
    #pragma unroll
    for (int nt = 0; nt < 4; ++nt) {
      int col = colBase + wn*64 + nt*16 + c15;
      #pragma unroll
      for (int r = 0; r < 4; ++r) {
        int row = rowBase + wm*64 + mt*16 + quad*4 + r;
        size_t idx = (size_t)row*N + col;
        float e = __expf(acc[mt][nt][r]);
        C8[idx] = f2e4m3(e);
        csum[nt] += e;
      }
    }
  }
  float* cs = (float*)lA;   // [2][128], reuses dead lA
  #pragma unroll
  for (int nt = 0; nt < 4; ++nt) {
    float s = csum[nt];
    s += __shfl_xor(s, 16, 64);
    s += __shfl_xor(s, 32, 64);
    if (lane < 16) cs[wm*128 + wn*64 + nt*16 + lane] = s;
  }
  __syncthreads();
  if (tid < 128)
    part[(size_t)(colBase + tid)*64 + rowTile] = cs[tid] + cs[128 + tid];
}

// ---------- GEMM2 (fp8): Ph[z] = (fp16) yhat8 * (w3*64)^T, split-K ----------
// 128x128 tile, BK=128 fp8, 16+16 KB LDS, XOR-swizzled 16B chunks.
// Grid (row=64, col=8, z=4): id%8 = rowTile%8 -> all col-tiles sharing an
// A-tile land on one XCD; per-XCD A+B working set ~2 MB stays L2-resident.
__global__ __launch_bounds__(256, 2)
void gemm_out(const unsigned char* __restrict__ A8,
              const unsigned char* __restrict__ B8,
              unsigned short* __restrict__ Ph,
              int K, int KCH, int N) {
  __shared__ unsigned char lA8[128*128];
  __shared__ unsigned char lB8[128*128];
  const int tid  = threadIdx.x;
  const int lane = tid & 63;
  const int wm   = (tid >> 6) >> 1, wn = (tid >> 6) & 1;
  const int rowBase = blockIdx.x * 128;
  const int colBase = blockIdx.y * 128;
  const int kStart  = blockIdx.z * KCH;

  v4f acc[4][4];
  #pragma unroll
  for (int i=0;i<4;++i)
    #pragma unroll
    for (int j=0;j<4;++j) acc[i][j] = (v4f){0.f,0.f,0.f,0.f};

  for (int k0 = kStart; k0 < kStart + KCH; k0 += 128) {
    #pragma unroll
    for (int j = 0; j < 4; ++j) {
      int s = j*256 + tid;
      int m = s >> 3;
      int c = (s & 7) ^ (m & 7);
      g2l16(A8 + (size_t)(rowBase + m)*K + k0 + c*16, &lA8[s*16]);
    }
    #pragma unroll
    for (int j = 0; j < 4; ++j) {
      int s = j*256 + tid;
      int m = s >> 3;
      int c = (s & 7) ^ (m & 7);
      g2l16(B8 + (size_t)(colBase + m)*K + k0 + c*16, &lB8[s*16]);
    }
    __syncthreads();
    #pragma unroll
    for (int s2 = 0; s2 < 4; ++s2) {
      const int quad = lane >> 4;
      const int cc = s2*2 + (quad >> 1);   // logical 16B chunk
      const int hh = quad & 1;             // 8B half within chunk
      long aF[4], bF[4];
      #pragma unroll
      for (int mt = 0; mt < 4; ++mt) {
        int ml = wm*64 + mt*16 + (lane & 15);
        aF[mt] = *(const long*)&lA8[ml*128 + ((cc ^ (ml & 7))<<4) + (hh<<3)];
      }
      #pragma unroll
      for (int nt = 0; nt < 4; ++nt) {
        int nl = wn*64 + nt*16 + (lane & 15);
        bF[nt] = *(const long*)&lB8[nl*128 + ((cc ^ (nl & 7))<<4) + (hh<<3)];
      }
      #pragma unroll
      for (int mt = 0; mt < 4; ++mt)
        #pragma unroll
        for (int nt = 0; nt < 4; ++nt)
          acc[mt][nt] = __builtin_amdgcn_mfma_f32_16x16x32_fp8_fp8(aF[mt], bF[nt], acc[mt][nt], 0, 0, 0);
    }
    __syncthreads();
  }

  const int quad = lane >> 4, c15 = lane & 15;
  #pragma unroll
  for (int mt = 0; mt < 4; ++mt) {
    #pragma unroll
    for (int nt = 0; nt < 4; ++nt) {
      int col = colBase + wn*64 + nt*16 + c15;
      #pragma unroll
      for (int r = 0; r < 4; ++r) {
        int row = rowBase + wm*64 + mt*16 + quad*4 + r;
        size_t idx = ((size_t)blockIdx.z*MROWS + row)*N + col;
        _Float16 h = (_Float16)acc[mt][nt][r];
        Ph[idx] = *(unsigned short*)&h;
      }
    }
  }
}

// ---------- exclusive prefix over 32 chunks per (col, batch) ----------
__global__ __launch_bounds__(256) void scan_prefix(float* __restrict__ part) {
  int idx = blockIdx.x*256 + threadIdx.x;   // 0..16383
  int col = idx >> 1, bb = idx & 1;
  float* p = part + (size_t)col*64 + bb*NCH;
  float run = 0.f;
  #pragma unroll
  for (int c = 0; c < NCH; ++c) { float v = p[c]; p[c] = run; run += v; }
}

// ---------- emit y = Sa*Sb/t^2 (bf16) from fp8 exp values ----------
__global__ __launch_bounds__(256) void scan_emit(const unsigned char* __restrict__ ab,
                                                 const float* __restrict__ part,
                                                 unsigned short* __restrict__ y) {
  int h = blockIdx.x*256 + threadIdx.x;     // 0..4095
  int cy = blockIdx.y, bb = blockIdx.z;
  float sa = part[(size_t)h*64 + bb*NCH + cy];
  float sb = part[(size_t)(HID + h)*64 + bb*NCH + cy];
  const unsigned char* pa = ab + ((size_t)(bb*TT + cy*CHUNK))*N1 + h;
  const unsigned char* pb = pa + HID;
  unsigned short* py = y + ((size_t)(bb*TT + cy*CHUNK))*HID + h;
  int t0 = cy*CHUNK;
  #pragma unroll 4
  for (int i = 0; i < CHUNK; ++i) {
    sa += e4m32f(pa[(size_t)i*N1]);
    sb += e4m32f(pb[(size_t)i*N1]);
    float inv = 1.0f / (float)(t0 + i + 1);
    py[(size_t)i*HID] = f2bf(sa*sb*inv*inv);
  }
}

// ---------- out = x + (1/64)*sum_z partial_z (fp16 partials) ----------
__global__ __launch_bounds__(256) void reduce_out(const unsigned short* __restrict__ p,
                                                  const float* __restrict__ x,
                                                  float* __restrict__ o) {
  size_t i = ((size_t)blockIdx.x*256 + threadIdx.x)*4;
  float4 xv = *(const float4*)(x + i);
  float s0 = 0.f, s1 = 0.f, s2 = 0.f, s3 = 0.f;
  #pragma unroll
  for (int z = 0; z < 4; ++z) {
    ushort4 u = *(const ushort4*)(p + (size_t)z*MROWS*EMB + i);
    s0 += h2f(u.x); s1 += h2f(u.y); s2 += h2f(u.z); s3 += h2f(u.w);
  }
  const float inv64 = 1.0f/64.0f;
  float4 ov; ov.x = xv.x + inv64*s0; ov.y = xv.y + inv64*s1;
             ov.z = xv.z + inv64*s2; ov.w = xv.w + inv64*s3;
  *(float4*)(o + i) = ov;
}

extern "C" void kernel_launch(void* const* d_in, const int* in_sizes, int n_in,
                              void* d_out, int out_size, void* d_ws, size_t ws_size,
                              hipStream_t stream) {
  const float* x  = (const float*)d_in[0];
  const float* W1 = (const float*)d_in[1];
  const float* W2 = (const float*)d_in[2];
  const float* W3 = (const float*)d_in[3];
  float* out = (float*)d_out;
  char* ws = (char*)d_ws;

  unsigned short* r_bf   = (unsigned short*)(ws);                 // 16 MiB
  unsigned short* w12_bf = (unsigned short*)(ws + 16777216ull);   // 16 MiB
  unsigned char*  w3_8   = (unsigned char*) (ws + 33554432ull);   // 4 MiB fp8 (x64)
  unsigned char*  ab8    = (unsigned char*) (ws + 37748736ull);   // 64 MiB fp8
  unsigned short* y_bf   = (unsigned short*)(ws + 104857600ull);  // 64 MiB
  unsigned char*  y8     = (unsigned char*) (ws + 171966464ull);  // 32 MiB fp8 (normalized)
  // psum (4 x 16 MiB fp16 GEMM2 partials) reuses dead ab8 (exactly 64 MiB)
  unsigned short* psum   = (unsigned short*)ab8;
  // part (per-chunk column sums) lives in d_out; dead before reduce_out
  float*          part   = (float*)d_out;                         // 2 MB

  conv_all<<<12288, 256, 0, stream>>>(W1, W2, W3, w12_bf, w3_8);
  rmsnorm_x<<<MROWS, 256, 0, stream>>>(x, r_bf);
  gemm_exp<<<4096, 256, 0, stream>>>(r_bf, w12_bf, ab8, part, EMB, N1);
  scan_prefix<<<64, 256, 0, stream>>>(part);
  scan_emit<<<dim3(16,NCH,2), 256, 0, stream>>>(ab8, part, y_bf);
  normq<<<MROWS, 256, 0, stream>>>(y_bf, y8);
  gemm_out<<<dim3(64,8,4), 256, 0, stream>>>(y8, w3_8, psum, HID, 1024, EMB);
  reduce_out<<<8192, 256, 0, stream>>>(psum, x, out);
}